// Round 3
// baseline (865.462 us; speedup 1.0000x reference)
//
#include <hip/hip_runtime.h>

#define N_NODES 100000
#define N_EDGES 1200000
#define NCLS 81  // 65 deg classes + 16 lab classes

typedef unsigned short u16;
typedef unsigned int u32;

__device__ __forceinline__ float b2f(u16 u) {
  union { u32 i; float f; } v; v.i = ((u32)u) << 16; return v.f;
}
__device__ __forceinline__ u16 f2b(float f) {
  union { float f; u32 i; } v; v.f = f;
  u32 x = v.i;
  return (u16)((x + 0x7fffu + ((x >> 16) & 1u)) >> 16);
}
__device__ __forceinline__ u32 pk2(float lo, float hi) {
  return (u32)f2b(lo) | ((u32)f2b(hi) << 16);
}
__device__ __forceinline__ void up2(u32 w, float& lo, float& hi) {
  union { u32 u; float f; } a, b;
  a.u = w << 16; b.u = w & 0xffff0000u;
  lo = a.f; hi = b.f;
}
__device__ __forceinline__ float lrelu(float x) { return x > 0.f ? x : 0.01f * x; }

// ---- fp32 param block offsets (element counts in comments) ----
#define P_EMBD 0       // 4160
#define P_EMBL 4160    // 1024
#define P_W1A  5184    // 16384  l0_w1 (128x128)
#define P_B1A  21568   // 128
#define P_W2A  21696   // 8192   l0_w2 (128x64)
#define P_B2A  29888   // 64
#define P_EPS0 29952   // 1
#define P_G0   29953   // 64
#define P_BB0  30017   // 64
#define P_LW1  30081   // 4096   l1_w1 (64x64)
#define P_LB1  34177   // 64
#define P_LW2  34241   // 4096   l1_w2 (64x64)
#define P_LB2  38337   // 64
#define P_EPS1 38401   // 1
#define P_G1   38402   // 64
#define P_BB1  38466   // 64
#define P_FW1  38530   // 16384  fc_w1 (256x64)
#define P_FB1  54914   // 64
#define P_FG   54978   // 64
#define P_FBB  55042   // 64
#define P_FW2  55106   // 64
#define P_FB2  55170   // 1
#define P_TOT  55171

// ---------------- dtype detection ----------------
// bf16 mode: every halfword of emb_deg has exponent field <= 0x7D (|x|<0.5).
// fp32 mode: even halfwords are uniform mantissa bits -> exp field >= 0x90 w.p. 0.44 each.
__global__ void k_detect(const u16* __restrict__ e, u32* __restrict__ flag) {
  u32 t = 0;
  for (int k = threadIdx.x; k < 4096; k += 256) {
    u32 ex = (e[k] >> 7) & 0xFF;
    if (ex >= 0x90) t = 1;
  }
  if (t) atomicOr(flag, 1u);
}

// ---------------- convert all float params to fp32 block ----------------
struct CvtAll {
  const void* src[22];
  int cnt[22];
  int off[22];
};

__global__ void k_cvtall(CvtAll a, const u32* __restrict__ flag, float* __restrict__ P) {
  int seg = blockIdx.y;
  int i = blockIdx.x * 256 + threadIdx.x;
  if (i >= a.cnt[seg]) return;
  float v;
  if (*flag) v = ((const float*)a.src[seg])[i];
  else       v = b2f(((const u16*)a.src[seg])[i]);
  P[a.off[seg] + i] = v;
}

// W1p[c][h] = (E @ l0_w1)[c][h]
__global__ void k_pre1(const float* __restrict__ P, float* __restrict__ W1p) {
  int idx = blockIdx.x * blockDim.x + threadIdx.x;
  if (idx >= NCLS * 128) return;
  int c = idx >> 7, h = idx & 127;
  const float* w1 = P + P_W1A;
  float s = 0.f;
  if (c < 65) {
    const float* em = P + P_EMBD + c * 64;
    for (int k = 0; k < 64; ++k) s = fmaf(em[k], w1[k * 128 + h], s);
  } else {
    const float* em = P + P_EMBL + (c - 65) * 64;
    for (int k = 0; k < 64; ++k) s = fmaf(em[k], w1[(64 + k) * 128 + h], s);
  }
  W1p[idx] = s;
}

// Efc[c][o] = (E @ fc_w1[0:128,:])[c][o]
__global__ void k_pre2(const float* __restrict__ P, float* __restrict__ Efc) {
  int idx = blockIdx.x * blockDim.x + threadIdx.x;
  if (idx >= NCLS * 64) return;
  int c = idx >> 6, o = idx & 63;
  const float* fw = P + P_FW1;
  float s = 0.f;
  if (c < 65) {
    const float* em = P + P_EMBD + c * 64;
    for (int k = 0; k < 64; ++k) s = fmaf(em[k], fw[k * 64 + o], s);
  } else {
    const float* em = P + P_EMBL + (c - 65) * 64;
    for (int k = 0; k < 64; ++k) s = fmaf(em[k], fw[(64 + k) * 64 + o], s);
  }
  Efc[idx] = s;
}

// ---------------- layer-0 class counts (packed u8) + in-degree ----------------
__global__ void k_count(const int* __restrict__ edge, const int* __restrict__ ndeg,
                        const int* __restrict__ nlab, u32* __restrict__ cntw,
                        u32* __restrict__ deg) {
  int e = blockIdx.x * blockDim.x + threadIdx.x;
  if (e >= N_EDGES) return;
  int s = edge[e], d = edge[N_EDGES + e];
  int i1 = ndeg[s] * N_NODES + d;
  int i2 = (65 + nlab[s]) * N_NODES + d;
  atomicAdd(&cntw[i1 >> 2], 1u << ((i1 & 3) * 8));
  atomicAdd(&cntw[i2 >> 2], 1u << ((i2 & 3) * 8));
  atomicAdd(&deg[d], 1u);
}

// ---------------- CSR build: scan of deg ----------------
__global__ void k_scan1(const u32* __restrict__ deg, u32* __restrict__ row_ptr,
                        u32* __restrict__ bsum) {
  __shared__ u32 l[256];
  int tid = threadIdx.x;
  int i = blockIdx.x * 256 + tid;
  u32 v = (i < N_NODES) ? deg[i] : 0u;
  l[tid] = v;
  __syncthreads();
  for (int off = 1; off < 256; off <<= 1) {
    u32 a = (tid >= off) ? l[tid - off] : 0u;
    __syncthreads();
    l[tid] += a;
    __syncthreads();
  }
  if (i < N_NODES) row_ptr[i] = l[tid] - v;
  if (tid == 255) bsum[blockIdx.x] = l[255];
}

#define NBLK_SCAN 391

__global__ void k_scan2(u32* __restrict__ bsum, u32* __restrict__ row_ptr) {
  __shared__ u32 l[512];
  int tid = threadIdx.x;
  u32 v = (tid < NBLK_SCAN) ? bsum[tid] : 0u;
  l[tid] = v;
  __syncthreads();
  for (int off = 1; off < 512; off <<= 1) {
    u32 a = (tid >= off) ? l[tid - off] : 0u;
    __syncthreads();
    l[tid] += a;
    __syncthreads();
  }
  if (tid < NBLK_SCAN) bsum[tid] = l[tid] - v;
  if (tid == NBLK_SCAN - 1) row_ptr[N_NODES] = l[tid];
}

__global__ void k_scan3(u32* __restrict__ row_ptr, const u32* __restrict__ bsum,
                        u32* __restrict__ cursor) {
  int i = blockIdx.x * 256 + threadIdx.x;
  if (i >= N_NODES) return;
  u32 v = row_ptr[i] + bsum[i >> 8];
  row_ptr[i] = v;
  cursor[i] = v;
}

__global__ void k_fill(const int* __restrict__ edge, u32* __restrict__ cursor,
                       u32* __restrict__ colidx) {
  int e = blockIdx.x * blockDim.x + threadIdx.x;
  if (e >= N_EDGES) return;
  int s = edge[e], d = edge[N_EDGES + e];
  u32 pos = atomicAdd(&cursor[d], 1u);
  colidx[pos] = (u32)s;
}

// ---------------- GIN layer 0 MLP ----------------
__global__ __launch_bounds__(128) void k_mlp0(const unsigned char* __restrict__ cnt,
                                              const int* __restrict__ ndeg,
                                              const int* __restrict__ nlab,
                                              const float* __restrict__ W1p,
                                              const float* __restrict__ P,
                                              u16* __restrict__ t) {
  __shared__ float lds[128 * 33];
  int n = blockIdx.x * 128 + threadIdx.x;
  if (n >= N_NODES) return;
  float onep = 1.f + P[P_EPS0];
  int dn = ndeg[n] * 128, ln = (65 + nlab[n]) * 128;
  const float* W2 = P + P_W2A;
  float acc[64];
#pragma unroll
  for (int o = 0; o < 64; ++o) acc[o] = P[P_B2A + o];
  float* myh = lds + threadIdx.x * 33;
#pragma unroll 1
  for (int hb = 0; hb < 4; ++hb) {
    float a1[32];
#pragma unroll
    for (int i = 0; i < 32; ++i)
      a1[i] = P[P_B1A + hb * 32 + i] + onep * (W1p[dn + hb * 32 + i] + W1p[ln + hb * 32 + i]);
#pragma unroll 1
    for (int c = 0; c < NCLS; ++c) {
      float cf = (float)cnt[c * N_NODES + n];
      const float* wr = W1p + c * 128 + hb * 32;
#pragma unroll
      for (int i = 0; i < 32; ++i) a1[i] = fmaf(cf, wr[i], a1[i]);
    }
#pragma unroll
    for (int i = 0; i < 32; ++i) myh[i] = lrelu(a1[i]);
#pragma unroll 1
    for (int i = 0; i < 32; ++i) {
      float h = myh[i];
      const float* w2r = W2 + (hb * 32 + i) * 64;
#pragma unroll
      for (int o = 0; o < 64; ++o) acc[o] = fmaf(h, w2r[o], acc[o]);
    }
  }
  u32* tn = (u32*)(t + (size_t)n * 64);
#pragma unroll
  for (int o2 = 0; o2 < 32; ++o2) tn[o2] = pk2(acc[2 * o2], acc[2 * o2 + 1]);
}

// ---------------- BatchNorm stats over bf16 t ----------------
__global__ void k_bnstats(const u16* __restrict__ t, float* __restrict__ stats) {
  __shared__ float ls[256], lq[256];
  int tid = threadIdx.x;
  int f = tid & 63, rg = tid >> 6;
  float s = 0.f, q = 0.f;
  for (int n = blockIdx.x * 4 + rg; n < N_NODES; n += gridDim.x * 4) {
    float v = b2f(t[(size_t)n * 64 + f]);
    s += v;
    q = fmaf(v, v, q);
  }
  ls[tid] = s; lq[tid] = q;
  __syncthreads();
  if (tid < 64) {
    s = ls[tid] + ls[tid + 64] + ls[tid + 128] + ls[tid + 192];
    q = lq[tid] + lq[tid + 64] + lq[tid + 128] + lq[tid + 192];
    atomicAdd(&stats[f], s);
    atomicAdd(&stats[64 + f], q);
  }
}

// ---------------- BN finalize + lrelu (bf16 in/out), g/b at P+goff/boff ----------------
__global__ void k_bnfin(const u16* __restrict__ t, const float* __restrict__ stats,
                        const float* __restrict__ P, int goff, int boff,
                        u16* __restrict__ h) {
  int idx = blockIdx.x * blockDim.x + threadIdx.x;
  if (idx >= N_NODES * 64) return;
  int f = idx & 63;
  const float invN = 1.f / (float)N_NODES;
  float m = stats[f] * invN;
  float var = fmaxf(stats[64 + f] * invN - m * m, 0.f);
  float inv = rsqrtf(var + 1e-5f);
  float v = (b2f(t[idx]) - m) * inv * P[goff + f] + P[boff + f];
  v = lrelu(v);
  if (!(fabsf(v) < 1e30f)) v = 999.0f;  // sentinel: non-finite upstream
  h[idx] = f2b(v);
}

// ---------------- layer-1 aggregation: CSR gather, wave-per-node ----------------
__global__ __launch_bounds__(256) void k_agg(const u32* __restrict__ row_ptr,
                                             const u32* __restrict__ colidx,
                                             const u16* __restrict__ h1,
                                             u16* __restrict__ agg) {
  int lane = threadIdx.x & 63, wid = threadIdx.x >> 6;
  int n = blockIdx.x * 4 + wid;
  if (n >= N_NODES) return;
  u32 b0 = row_ptr[n], b1 = row_ptr[n + 1];
  float acc = 0.f;
  for (u32 j = b0; j < b1; ++j) {
    u32 c = colidx[j];
    acc += b2f(h1[(size_t)c * 64 + lane]);
  }
  agg[(size_t)n * 64 + lane] = f2b(acc);
}

// ---------------- GIN layer 1 MLP ----------------
__global__ __launch_bounds__(128) void k_mlp1(const u16* __restrict__ h1,
                                              const u16* __restrict__ agg,
                                              const float* __restrict__ P,
                                              u16* __restrict__ t) {
  __shared__ float lds[128 * 33];
  int n = blockIdx.x * 128 + threadIdx.x;
  if (n >= N_NODES) return;
  float onep = 1.f + P[P_EPS1];
  const float* w1f = P + P_LW1;
  const float* w2f = P + P_LW2;
  float acc[64];
#pragma unroll
  for (int o = 0; o < 64; ++o) acc[o] = P[P_LB2 + o];
  const uint4* hv = (const uint4*)(h1 + (size_t)n * 64);
  const uint4* av = (const uint4*)(agg + (size_t)n * 64);
  float* myh = lds + threadIdx.x * 33;
#pragma unroll 1
  for (int hb = 0; hb < 2; ++hb) {
    float a1[32];
#pragma unroll
    for (int i = 0; i < 32; ++i) a1[i] = P[P_LB1 + hb * 32 + i];
#pragma unroll 1
    for (int kb = 0; kb < 8; ++kb) {
      uint4 hq = hv[kb], aq = av[kb];
      float xh[8], xa[8];
      up2(hq.x, xh[0], xh[1]); up2(hq.y, xh[2], xh[3]);
      up2(hq.z, xh[4], xh[5]); up2(hq.w, xh[6], xh[7]);
      up2(aq.x, xa[0], xa[1]); up2(aq.y, xa[2], xa[3]);
      up2(aq.z, xa[4], xa[5]); up2(aq.w, xa[6], xa[7]);
      const float* wr = w1f + (kb * 8) * 64 + hb * 32;
#pragma unroll
      for (int j = 0; j < 8; ++j) {
        float xx = fmaf(onep, xh[j], xa[j]);
#pragma unroll
        for (int i = 0; i < 32; ++i) a1[i] = fmaf(xx, wr[j * 64 + i], a1[i]);
      }
    }
#pragma unroll
    for (int i = 0; i < 32; ++i) myh[i] = lrelu(a1[i]);
#pragma unroll 1
    for (int i = 0; i < 32; ++i) {
      float h = myh[i];
      const float* w2r = w2f + (hb * 32 + i) * 64;
#pragma unroll
      for (int o = 0; o < 64; ++o) acc[o] = fmaf(h, w2r[o], acc[o]);
    }
  }
  u32* tn = (u32*)(t + (size_t)n * 64);
#pragma unroll
  for (int o2 = 0; o2 < 32; ++o2) tn[o2] = pk2(acc[2 * o2], acc[2 * o2 + 1]);
}

// ---------------- FC layer 1 ----------------
__global__ __launch_bounds__(128) void k_fc1(const int* __restrict__ ndeg,
                                             const int* __restrict__ nlab,
                                             const float* __restrict__ Efc,
                                             const u16* __restrict__ h1,
                                             const u16* __restrict__ h2,
                                             const float* __restrict__ P,
                                             u16* __restrict__ t) {
  int n = blockIdx.x * 128 + threadIdx.x;
  if (n >= N_NODES) return;
  const float* fw = P + P_FW1;
  float acc[64];
  int dn = ndeg[n], ln = 65 + nlab[n];
  const float4* e1 = (const float4*)(Efc + dn * 64);
  const float4* e2 = (const float4*)(Efc + ln * 64);
#pragma unroll
  for (int ob = 0; ob < 16; ++ob) {
    float4 a = e1[ob], b = e2[ob];
    acc[ob * 4 + 0] = P[P_FB1 + ob * 4 + 0] + a.x + b.x;
    acc[ob * 4 + 1] = P[P_FB1 + ob * 4 + 1] + a.y + b.y;
    acc[ob * 4 + 2] = P[P_FB1 + ob * 4 + 2] + a.z + b.z;
    acc[ob * 4 + 3] = P[P_FB1 + ob * 4 + 3] + a.w + b.w;
  }
  const uint4* xv = (const uint4*)(h1 + (size_t)n * 64);
#pragma unroll 1
  for (int kb = 0; kb < 8; ++kb) {
    uint4 q = xv[kb];
    float x[8];
    up2(q.x, x[0], x[1]); up2(q.y, x[2], x[3]);
    up2(q.z, x[4], x[5]); up2(q.w, x[6], x[7]);
    const float* wr = fw + (128 + kb * 8) * 64;
#pragma unroll
    for (int j = 0; j < 8; ++j)
#pragma unroll
      for (int o = 0; o < 64; ++o) acc[o] = fmaf(x[j], wr[j * 64 + o], acc[o]);
  }
  xv = (const uint4*)(h2 + (size_t)n * 64);
#pragma unroll 1
  for (int kb = 0; kb < 8; ++kb) {
    uint4 q = xv[kb];
    float x[8];
    up2(q.x, x[0], x[1]); up2(q.y, x[2], x[3]);
    up2(q.z, x[4], x[5]); up2(q.w, x[6], x[7]);
    const float* wr = fw + (192 + kb * 8) * 64;
#pragma unroll
    for (int j = 0; j < 8; ++j)
#pragma unroll
      for (int o = 0; o < 64; ++o) acc[o] = fmaf(x[j], wr[j * 64 + o], acc[o]);
  }
  u32* tn = (u32*)(t + (size_t)n * 64);
#pragma unroll
  for (int o2 = 0; o2 < 32; ++o2) tn[o2] = pk2(acc[2 * o2], acc[2 * o2 + 1]);
}

// ---------------- FC final: BN + lrelu + dot + sigmoid, dual-dtype out ----------------
__global__ void k_fc2(const u16* __restrict__ t, const float* __restrict__ stats,
                      const float* __restrict__ P, const u32* __restrict__ flag,
                      void* __restrict__ out) {
  int n = blockIdx.x * blockDim.x + threadIdx.x;
  if (n >= N_NODES) return;
  float z = P[P_FB2];
  const float invN = 1.f / (float)N_NODES;
  const uint4* tv = (const uint4*)(t + (size_t)n * 64);
#pragma unroll 1
  for (int fb = 0; fb < 8; ++fb) {
    uint4 q = tv[fb];
    float v[8];
    up2(q.x, v[0], v[1]); up2(q.y, v[2], v[3]);
    up2(q.z, v[4], v[5]); up2(q.w, v[6], v[7]);
#pragma unroll
    for (int j = 0; j < 8; ++j) {
      int f = fb * 8 + j;
      float m = stats[f] * invN;
      float var = fmaxf(stats[64 + f] * invN - m * m, 0.f);
      float inv = rsqrtf(var + 1e-5f);
      float y = (v[j] - m) * inv * P[P_FG + f] + P[P_FBB + f];
      y = lrelu(y);
      z = fmaf(y, P[P_FW2 + f], z);
    }
  }
  float s = 1.f / (1.f + expf(-z));
  if (!(fabsf(z) < 1e30f)) s = 0.25f;  // sentinel: non-finite reached fc2
  if (*flag) ((float*)out)[n] = s;
  else       ((u16*)out)[n] = f2b(s);
}

extern "C" void kernel_launch(void* const* d_in, const int* in_sizes, int n_in,
                              void* d_out, int out_size, void* d_ws, size_t ws_size,
                              hipStream_t stream) {
  const int* node_deg = (const int*)d_in[0];
  const int* node_lab = (const int*)d_in[1];
  const int* edge     = (const int*)d_in[2];
  (void)in_sizes; (void)n_in; (void)out_size; (void)ws_size;

  char* base = (char*)d_ws;
  size_t off = 0;
  auto alloc = [&](size_t bytes) -> void* {
    void* p = base + off;
    off += (bytes + 15) & ~(size_t)15;
    return p;
  };
  float* Pb    = (float*)alloc((size_t)P_TOT * 4);
  u32* flag    = (u32*)alloc(16);
  float* W1p   = (float*)alloc(NCLS * 128 * 4);
  float* Efc   = (float*)alloc(NCLS * 64 * 4);
  float* stats = (float*)alloc(384 * 4);
  u32* deg     = (u32*)alloc((size_t)N_NODES * 4);
  u32* row_ptr = (u32*)alloc((size_t)(N_NODES + 1) * 4);
  u32* cursor  = (u32*)alloc((size_t)N_NODES * 4);
  u32* bsum    = (u32*)alloc(512 * 4);
  u32* colidx  = (u32*)alloc((size_t)N_EDGES * 4);
  void* arena  = alloc((size_t)N_NODES * 64 * 2);  // counts (8.1MB) then agg (12.8MB)
  u16* h1      = (u16*)alloc((size_t)N_NODES * 64 * 2);
  u16* h2      = (u16*)alloc((size_t)N_NODES * 64 * 2);
  u16* t       = (u16*)alloc((size_t)N_NODES * 64 * 2);
  unsigned char* counts = (unsigned char*)arena;
  u16* agg = (u16*)arena;

  hipMemsetAsync(flag, 0, 16, stream);
  hipMemsetAsync(stats, 0, 384 * 4, stream);
  hipMemsetAsync(counts, 0, (size_t)NCLS * N_NODES, stream);
  hipMemsetAsync(deg, 0, (size_t)N_NODES * 4, stream);

  k_detect<<<1, 256, 0, stream>>>((const u16*)d_in[3], flag);

  CvtAll ca;
  const int srcidx[22] = {3, 4, 5, 6, 7, 8, 9, 10, 11, 12, 13, 14, 15, 16, 17, 18, 19, 20, 21, 22, 23, 24};
  const int cnts[22]   = {4160, 1024, 16384, 128, 8192, 64, 1, 64, 64, 4096, 64, 4096, 64, 1, 64, 64, 16384, 64, 64, 64, 64, 1};
  const int offs[22]   = {P_EMBD, P_EMBL, P_W1A, P_B1A, P_W2A, P_B2A, P_EPS0, P_G0, P_BB0,
                          P_LW1, P_LB1, P_LW2, P_LB2, P_EPS1, P_G1, P_BB1,
                          P_FW1, P_FB1, P_FG, P_FBB, P_FW2, P_FB2};
  for (int i = 0; i < 22; ++i) { ca.src[i] = d_in[srcidx[i]]; ca.cnt[i] = cnts[i]; ca.off[i] = offs[i]; }
  k_cvtall<<<dim3(64, 22), 256, 0, stream>>>(ca, flag, Pb);

  k_pre1<<<(NCLS * 128 + 255) / 256, 256, 0, stream>>>(Pb, W1p);
  k_pre2<<<(NCLS * 64 + 255) / 256, 256, 0, stream>>>(Pb, Efc);

  k_count<<<(N_EDGES + 255) / 256, 256, 0, stream>>>(edge, node_deg, node_lab, (u32*)counts, deg);

  // CSR build
  k_scan1<<<NBLK_SCAN, 256, 0, stream>>>(deg, row_ptr, bsum);
  k_scan2<<<1, 512, 0, stream>>>(bsum, row_ptr);
  k_scan3<<<NBLK_SCAN, 256, 0, stream>>>(row_ptr, bsum, cursor);
  k_fill<<<(N_EDGES + 255) / 256, 256, 0, stream>>>(edge, cursor, colidx);

  // layer 0
  k_mlp0<<<(N_NODES + 127) / 128, 128, 0, stream>>>(counts, node_deg, node_lab, W1p, Pb, t);
  k_bnstats<<<256, 256, 0, stream>>>(t, stats);
  k_bnfin<<<(N_NODES * 64 + 255) / 256, 256, 0, stream>>>(t, stats, Pb, P_G0, P_BB0, h1);

  // layer 1 (agg reuses the counts arena — counts dead after k_mlp0)
  k_agg<<<(N_NODES + 3) / 4, 256, 0, stream>>>(row_ptr, colidx, h1, agg);
  k_mlp1<<<(N_NODES + 127) / 128, 128, 0, stream>>>(h1, agg, Pb, t);
  k_bnstats<<<256, 256, 0, stream>>>(t, stats + 128);
  k_bnfin<<<(N_NODES * 64 + 255) / 256, 256, 0, stream>>>(t, stats + 128, Pb, P_G1, P_BB1, h2);

  // FC head
  k_fc1<<<(N_NODES + 127) / 128, 128, 0, stream>>>(node_deg, node_lab, Efc, h1, h2, Pb, t);
  k_bnstats<<<256, 256, 0, stream>>>(t, stats + 256);
  k_fc2<<<(N_NODES + 255) / 256, 256, 0, stream>>>(t, stats + 256, Pb, flag, d_out);
}

// Round 4
// 758.963 us; speedup vs baseline: 1.1403x; 1.1403x over previous
//
#include <hip/hip_runtime.h>

#define N_NODES 100000
#define N_EDGES 1200000
#define NCLS 81  // 65 deg classes + 16 lab classes

typedef unsigned short u16;
typedef unsigned int u32;

__device__ __forceinline__ float b2f(u16 u) {
  union { u32 i; float f; } v; v.i = ((u32)u) << 16; return v.f;
}
__device__ __forceinline__ u16 f2b(float f) {
  union { float f; u32 i; } v; v.f = f;
  u32 x = v.i;
  return (u16)((x + 0x7fffu + ((x >> 16) & 1u)) >> 16);
}
__device__ __forceinline__ u32 pk2(float lo, float hi) {
  return (u32)f2b(lo) | ((u32)f2b(hi) << 16);
}
__device__ __forceinline__ void up2(u32 w, float& lo, float& hi) {
  union { u32 u; float f; } a, b;
  a.u = w << 16; b.u = w & 0xffff0000u;
  lo = a.f; hi = b.f;
}
__device__ __forceinline__ float lrelu(float x) { return x > 0.f ? x : 0.01f * x; }

// ---- fp32 param block offsets ----
#define P_EMBD 0       // 4160
#define P_EMBL 4160    // 1024
#define P_W1A  5184    // 16384  l0_w1 (128x128)
#define P_B1A  21568   // 128
#define P_W2A  21696   // 8192   l0_w2 (128x64)
#define P_B2A  29888   // 64
#define P_EPS0 29952   // 1
#define P_G0   29953   // 64
#define P_BB0  30017   // 64
#define P_LW1  30081   // 4096   l1_w1 (64x64)
#define P_LB1  34177   // 64
#define P_LW2  34241   // 4096   l1_w2 (64x64)
#define P_LB2  38337   // 64
#define P_EPS1 38401   // 1
#define P_G1   38402   // 64
#define P_BB1  38466   // 64
#define P_FW1  38530   // 16384  fc_w1 (256x64)
#define P_FB1  54914   // 64
#define P_FG   54978   // 64
#define P_FBB  55042   // 64
#define P_FW2  55106   // 64
#define P_FB2  55170   // 1
#define P_TOT  55171

// ---------------- dtype detection ----------------
__global__ void k_detect(const u16* __restrict__ e, u32* __restrict__ flag) {
  u32 t = 0;
  for (int k = threadIdx.x; k < 4096; k += 256) {
    u32 ex = (e[k] >> 7) & 0xFF;
    if (ex >= 0x90) t = 1;
  }
  if (t) atomicOr(flag, 1u);
}

// ---------------- convert all float params to fp32 block ----------------
struct CvtAll {
  const void* src[22];
  int cnt[22];
  int off[22];
};

__global__ void k_cvtall(CvtAll a, const u32* __restrict__ flag, float* __restrict__ P) {
  int seg = blockIdx.y;
  int i = blockIdx.x * 256 + threadIdx.x;
  if (i >= a.cnt[seg]) return;
  float v;
  if (*flag) v = ((const float*)a.src[seg])[i];
  else       v = b2f(((const u16*)a.src[seg])[i]);
  P[a.off[seg] + i] = v;
}

// W1p[c][h] = (E @ l0_w1)[c][h]
__global__ void k_pre1(const float* __restrict__ P, float* __restrict__ W1p) {
  int idx = blockIdx.x * blockDim.x + threadIdx.x;
  if (idx >= NCLS * 128) return;
  int c = idx >> 7, h = idx & 127;
  const float* w1 = P + P_W1A;
  float s = 0.f;
  if (c < 65) {
    const float* em = P + P_EMBD + c * 64;
    for (int k = 0; k < 64; ++k) s = fmaf(em[k], w1[k * 128 + h], s);
  } else {
    const float* em = P + P_EMBL + (c - 65) * 64;
    for (int k = 0; k < 64; ++k) s = fmaf(em[k], w1[(64 + k) * 128 + h], s);
  }
  W1p[idx] = s;
}

// Efc[c][o] = (E @ fc_w1[0:128,:])[c][o]
__global__ void k_pre2(const float* __restrict__ P, float* __restrict__ Efc) {
  int idx = blockIdx.x * blockDim.x + threadIdx.x;
  if (idx >= NCLS * 64) return;
  int c = idx >> 6, o = idx & 63;
  const float* fw = P + P_FW1;
  float s = 0.f;
  if (c < 65) {
    const float* em = P + P_EMBD + c * 64;
    for (int k = 0; k < 64; ++k) s = fmaf(em[k], fw[k * 64 + o], s);
  } else {
    const float* em = P + P_EMBL + (c - 65) * 64;
    for (int k = 0; k < 64; ++k) s = fmaf(em[k], fw[(64 + k) * 64 + o], s);
  }
  Efc[idx] = s;
}

// ---------------- in-degree ----------------
__global__ void k_deg(const int* __restrict__ edge, u32* __restrict__ deg) {
  int e = blockIdx.x * 256 + threadIdx.x;
  if (e >= N_EDGES) return;
  atomicAdd(&deg[edge[N_EDGES + e]], 1u);
}

// ---------------- CSR build: scan of deg ----------------
__global__ void k_scan1(const u32* __restrict__ deg, u32* __restrict__ row_ptr,
                        u32* __restrict__ bsum) {
  __shared__ u32 l[256];
  int tid = threadIdx.x;
  int i = blockIdx.x * 256 + tid;
  u32 v = (i < N_NODES) ? deg[i] : 0u;
  l[tid] = v;
  __syncthreads();
  for (int off = 1; off < 256; off <<= 1) {
    u32 a = (tid >= off) ? l[tid - off] : 0u;
    __syncthreads();
    l[tid] += a;
    __syncthreads();
  }
  if (i < N_NODES) row_ptr[i] = l[tid] - v;
  if (tid == 255) bsum[blockIdx.x] = l[255];
}

#define NBLK_SCAN 391

__global__ void k_scan2(u32* __restrict__ bsum, u32* __restrict__ row_ptr) {
  __shared__ u32 l[512];
  int tid = threadIdx.x;
  u32 v = (tid < NBLK_SCAN) ? bsum[tid] : 0u;
  l[tid] = v;
  __syncthreads();
  for (int off = 1; off < 512; off <<= 1) {
    u32 a = (tid >= off) ? l[tid - off] : 0u;
    __syncthreads();
    l[tid] += a;
    __syncthreads();
  }
  if (tid < NBLK_SCAN) bsum[tid] = l[tid] - v;
  if (tid == NBLK_SCAN - 1) row_ptr[N_NODES] = l[tid];
}

__global__ void k_scan3(u32* __restrict__ row_ptr, const u32* __restrict__ bsum,
                        u32* __restrict__ cursor) {
  int i = blockIdx.x * 256 + threadIdx.x;
  if (i >= N_NODES) return;
  u32 v = row_ptr[i] + bsum[i >> 8];
  row_ptr[i] = v;
  cursor[i] = v;
}

// ---------------- CSR fill: colidx (src id) + ccls (packed src classes) ----------------
__global__ void k_fill(const int* __restrict__ edge, const int* __restrict__ ndeg,
                       const int* __restrict__ nlab, u32* __restrict__ cursor,
                       u32* __restrict__ colidx, u16* __restrict__ ccls) {
  int e = blockIdx.x * 256 + threadIdx.x;
  if (e >= N_EDGES) return;
  int s = edge[e], d = edge[N_EDGES + e];
  u32 pos = atomicAdd(&cursor[d], 1u);
  colidx[pos] = (u32)s;
  ccls[pos] = (u16)((ndeg[s] << 4) | nlab[s]);  // deg 0..64 (7b) | lab 0..15 (4b)
}

// ---------------- layer-0 aggregation: LDS-resident W1p row gather ----------------
// hmid[n][0:128] = lrelu(b1 + (1+eps)(W1p[dn]+W1p[ln]) + sum_nbr (W1p[cd]+W1p[cl]))
__global__ __launch_bounds__(256) void k_agg0(const u32* __restrict__ row_ptr,
                                              const u16* __restrict__ ccls,
                                              const int* __restrict__ ndeg,
                                              const int* __restrict__ nlab,
                                              const float* __restrict__ W1p,
                                              const float* __restrict__ P,
                                              u16* __restrict__ hmid) {
  __shared__ float w[NCLS * 128];  // 41472 B
  for (int i = threadIdx.x; i < NCLS * 32; i += 256)
    ((float4*)w)[i] = ((const float4*)W1p)[i];
  __syncthreads();
  const float2* w2 = (const float2*)w;
  int lane = threadIdx.x & 63, wv = threadIdx.x >> 6;
  float onep = 1.f + P[P_EPS0];
  float2 b1v = ((const float2*)(P + P_B1A))[lane];
#pragma unroll 1
  for (int it = 0; it < 16; ++it) {
    int n = blockIdx.x * 64 + it * 4 + wv;
    if (n >= N_NODES) continue;
    int dn = ndeg[n], ln = 65 + nlab[n];
    float2 vd = w2[dn * 64 + lane];
    float2 vl = w2[ln * 64 + lane];
    float a0 = b1v.x + onep * (vd.x + vl.x);
    float a1 = b1v.y + onep * (vd.y + vl.y);
    u32 b0 = row_ptr[n], b1 = row_ptr[n + 1];
    for (u32 base = b0; base < b1; base += 64) {
      u32 m = b1 - base; if (m > 64u) m = 64u;
      u32 myc = ((u32)lane < m) ? (u32)ccls[base + lane] : 0u;
      for (u32 kk = 0; kk < m; ++kk) {
        u32 cc = (u32)__builtin_amdgcn_readlane((int)myc, (int)kk);
        int cd = (int)(cc >> 4), cl = 65 + (int)(cc & 15u);
        float2 xd = w2[cd * 64 + lane];
        float2 xl = w2[cl * 64 + lane];
        a0 += xd.x + xl.x;
        a1 += xd.y + xl.y;
      }
    }
    ((u32*)hmid)[(size_t)n * 64 + lane] = pk2(lrelu(a0), lrelu(a1));
  }
}

// ---------------- GEMM16 kernels: 4 threads/node (sub=wave), 16 outputs each ----------
// t[n] = hmid[n] (128) @ W2A + b2
__global__ __launch_bounds__(256) void k_mlp0b(const u16* __restrict__ hmid,
                                               const float* __restrict__ P,
                                               u16* __restrict__ t) {
  int lane = threadIdx.x & 63;
  int sub = __builtin_amdgcn_readfirstlane((int)(threadIdx.x >> 6));
  int n = blockIdx.x * 64 + lane;
  if (n >= N_NODES) return;
  const float* W = P + P_W2A + sub * 16;
  float acc[16];
#pragma unroll
  for (int i = 0; i < 16; ++i) acc[i] = P[P_B2A + sub * 16 + i];
  const uint4* xv = (const uint4*)(hmid + (size_t)n * 128);
#pragma unroll
  for (int kb = 0; kb < 16; ++kb) {
    uint4 q = xv[kb];
    float x[8];
    up2(q.x, x[0], x[1]); up2(q.y, x[2], x[3]);
    up2(q.z, x[4], x[5]); up2(q.w, x[6], x[7]);
#pragma unroll
    for (int j = 0; j < 8; ++j) {
      const float* wr = W + (kb * 8 + j) * 64;
#pragma unroll
      for (int i = 0; i < 16; ++i) acc[i] = fmaf(x[j], wr[i], acc[i]);
    }
  }
  u32* tn = (u32*)(t + (size_t)n * 64 + sub * 16);
#pragma unroll
  for (int i2 = 0; i2 < 8; ++i2) tn[i2] = pk2(acc[2 * i2], acc[2 * i2 + 1]);
}

// g1[n] = h1[n] (64) @ LW1   (no bias; bias/eps applied post-aggregation)
__global__ __launch_bounds__(256) void k_g1(const u16* __restrict__ h1,
                                            const float* __restrict__ P,
                                            u16* __restrict__ g1) {
  int lane = threadIdx.x & 63;
  int sub = __builtin_amdgcn_readfirstlane((int)(threadIdx.x >> 6));
  int n = blockIdx.x * 64 + lane;
  if (n >= N_NODES) return;
  const float* W = P + P_LW1 + sub * 16;
  float acc[16];
#pragma unroll
  for (int i = 0; i < 16; ++i) acc[i] = 0.f;
  const uint4* xv = (const uint4*)(h1 + (size_t)n * 64);
#pragma unroll
  for (int kb = 0; kb < 8; ++kb) {
    uint4 q = xv[kb];
    float x[8];
    up2(q.x, x[0], x[1]); up2(q.y, x[2], x[3]);
    up2(q.z, x[4], x[5]); up2(q.w, x[6], x[7]);
#pragma unroll
    for (int j = 0; j < 8; ++j) {
      const float* wr = W + (kb * 8 + j) * 64;
#pragma unroll
      for (int i = 0; i < 16; ++i) acc[i] = fmaf(x[j], wr[i], acc[i]);
    }
  }
  u32* gn = (u32*)(g1 + (size_t)n * 64 + sub * 16);
#pragma unroll
  for (int i2 = 0; i2 < 8; ++i2) gn[i2] = pk2(acc[2 * i2], acc[2 * i2 + 1]);
}

// a[n] = lrelu(b1 + (1+eps1)*g1[n] + sum_nbr g1[nbr])   — aggregate AFTER GEMM
__global__ __launch_bounds__(256) void k_agg1(const u32* __restrict__ row_ptr,
                                              const u32* __restrict__ colidx,
                                              const u16* __restrict__ g1,
                                              const float* __restrict__ P,
                                              u16* __restrict__ abuf) {
  int lane = threadIdx.x & 63, wv = threadIdx.x >> 6;
  int n = blockIdx.x * 4 + wv;
  if (n >= N_NODES) return;
  u32 b0 = row_ptr[n], b1 = row_ptr[n + 1];
  u32 m = b1 - b0;
  float acc = 0.f;
  u32 k = 0;
  for (; k + 4 <= m; k += 4) {
    u32 c0 = colidx[b0 + k], c1 = colidx[b0 + k + 1];
    u32 c2 = colidx[b0 + k + 2], c3 = colidx[b0 + k + 3];
    float v0 = b2f(g1[(size_t)c0 * 64 + lane]);
    float v1 = b2f(g1[(size_t)c1 * 64 + lane]);
    float v2 = b2f(g1[(size_t)c2 * 64 + lane]);
    float v3 = b2f(g1[(size_t)c3 * 64 + lane]);
    acc += (v0 + v1) + (v2 + v3);
  }
  for (; k < m; ++k) acc += b2f(g1[(size_t)colidx[b0 + k] * 64 + lane]);
  float onep = 1.f + P[P_EPS1];
  float a = P[P_LB1 + lane] + fmaf(onep, b2f(g1[(size_t)n * 64 + lane]), acc);
  abuf[(size_t)n * 64 + lane] = f2b(lrelu(a));
}

// t[n] = a[n] (64) @ LW2 + lb2
__global__ __launch_bounds__(256) void k_g2(const u16* __restrict__ abuf,
                                            const float* __restrict__ P,
                                            u16* __restrict__ t) {
  int lane = threadIdx.x & 63;
  int sub = __builtin_amdgcn_readfirstlane((int)(threadIdx.x >> 6));
  int n = blockIdx.x * 64 + lane;
  if (n >= N_NODES) return;
  const float* W = P + P_LW2 + sub * 16;
  float acc[16];
#pragma unroll
  for (int i = 0; i < 16; ++i) acc[i] = P[P_LB2 + sub * 16 + i];
  const uint4* xv = (const uint4*)(abuf + (size_t)n * 64);
#pragma unroll
  for (int kb = 0; kb < 8; ++kb) {
    uint4 q = xv[kb];
    float x[8];
    up2(q.x, x[0], x[1]); up2(q.y, x[2], x[3]);
    up2(q.z, x[4], x[5]); up2(q.w, x[6], x[7]);
#pragma unroll
    for (int j = 0; j < 8; ++j) {
      const float* wr = W + (kb * 8 + j) * 64;
#pragma unroll
      for (int i = 0; i < 16; ++i) acc[i] = fmaf(x[j], wr[i], acc[i]);
    }
  }
  u32* tn = (u32*)(t + (size_t)n * 64 + sub * 16);
#pragma unroll
  for (int i2 = 0; i2 < 8; ++i2) tn[i2] = pk2(acc[2 * i2], acc[2 * i2 + 1]);
}

// t[n] = [h0;h1;h2](256) @ FW1 + fb1  (h0 part via Efc row gathers)
__global__ __launch_bounds__(256) void k_fc1b(const int* __restrict__ ndeg,
                                              const int* __restrict__ nlab,
                                              const float* __restrict__ Efc,
                                              const u16* __restrict__ h1,
                                              const u16* __restrict__ h2,
                                              const float* __restrict__ P,
                                              u16* __restrict__ t) {
  int lane = threadIdx.x & 63;
  int sub = __builtin_amdgcn_readfirstlane((int)(threadIdx.x >> 6));
  int n = blockIdx.x * 64 + lane;
  if (n >= N_NODES) return;
  int dn = ndeg[n], ln = 65 + nlab[n];
  const float4* e1 = (const float4*)(Efc + dn * 64 + sub * 16);
  const float4* e2 = (const float4*)(Efc + ln * 64 + sub * 16);
  float acc[16];
#pragma unroll
  for (int q4 = 0; q4 < 4; ++q4) {
    float4 a = e1[q4], b = e2[q4];
    acc[q4 * 4 + 0] = P[P_FB1 + sub * 16 + q4 * 4 + 0] + a.x + b.x;
    acc[q4 * 4 + 1] = P[P_FB1 + sub * 16 + q4 * 4 + 1] + a.y + b.y;
    acc[q4 * 4 + 2] = P[P_FB1 + sub * 16 + q4 * 4 + 2] + a.z + b.z;
    acc[q4 * 4 + 3] = P[P_FB1 + sub * 16 + q4 * 4 + 3] + a.w + b.w;
  }
  const uint4* xv = (const uint4*)(h1 + (size_t)n * 64);
  const float* W = P + P_FW1 + 128 * 64 + sub * 16;
#pragma unroll
  for (int kb = 0; kb < 8; ++kb) {
    uint4 q = xv[kb];
    float x[8];
    up2(q.x, x[0], x[1]); up2(q.y, x[2], x[3]);
    up2(q.z, x[4], x[5]); up2(q.w, x[6], x[7]);
#pragma unroll
    for (int j = 0; j < 8; ++j) {
      const float* wr = W + (kb * 8 + j) * 64;
#pragma unroll
      for (int i = 0; i < 16; ++i) acc[i] = fmaf(x[j], wr[i], acc[i]);
    }
  }
  xv = (const uint4*)(h2 + (size_t)n * 64);
  W = P + P_FW1 + 192 * 64 + sub * 16;
#pragma unroll
  for (int kb = 0; kb < 8; ++kb) {
    uint4 q = xv[kb];
    float x[8];
    up2(q.x, x[0], x[1]); up2(q.y, x[2], x[3]);
    up2(q.z, x[4], x[5]); up2(q.w, x[6], x[7]);
#pragma unroll
    for (int j = 0; j < 8; ++j) {
      const float* wr = W + (kb * 8 + j) * 64;
#pragma unroll
      for (int i = 0; i < 16; ++i) acc[i] = fmaf(x[j], wr[i], acc[i]);
    }
  }
  u32* tn = (u32*)(t + (size_t)n * 64 + sub * 16);
#pragma unroll
  for (int i2 = 0; i2 < 8; ++i2) tn[i2] = pk2(acc[2 * i2], acc[2 * i2 + 1]);
}

// ---------------- BatchNorm stats over bf16 t ----------------
__global__ void k_bnstats(const u16* __restrict__ t, float* __restrict__ stats) {
  __shared__ float ls[256], lq[256];
  int tid = threadIdx.x;
  int f = tid & 63, rg = tid >> 6;
  float s = 0.f, q = 0.f;
  for (int n = blockIdx.x * 4 + rg; n < N_NODES; n += gridDim.x * 4) {
    float v = b2f(t[(size_t)n * 64 + f]);
    s += v;
    q = fmaf(v, v, q);
  }
  ls[tid] = s; lq[tid] = q;
  __syncthreads();
  if (tid < 64) {
    s = ls[tid] + ls[tid + 64] + ls[tid + 128] + ls[tid + 192];
    q = lq[tid] + lq[tid + 64] + lq[tid + 128] + lq[tid + 192];
    atomicAdd(&stats[f], s);
    atomicAdd(&stats[64 + f], q);
  }
}

// ---------------- BN finalize + lrelu (bf16 in/out) ----------------
__global__ void k_bnfin(const u16* __restrict__ t, const float* __restrict__ stats,
                        const float* __restrict__ P, int goff, int boff,
                        u16* __restrict__ h) {
  int idx = blockIdx.x * blockDim.x + threadIdx.x;
  if (idx >= N_NODES * 64) return;
  int f = idx & 63;
  const float invN = 1.f / (float)N_NODES;
  float m = stats[f] * invN;
  float var = fmaxf(stats[64 + f] * invN - m * m, 0.f);
  float inv = rsqrtf(var + 1e-5f);
  float v = (b2f(t[idx]) - m) * inv * P[goff + f] + P[boff + f];
  v = lrelu(v);
  if (!(fabsf(v) < 1e30f)) v = 999.0f;
  h[idx] = f2b(v);
}

// ---------------- FC final: BN + lrelu + dot + sigmoid ----------------
__global__ void k_fc2(const u16* __restrict__ t, const float* __restrict__ stats,
                      const float* __restrict__ P, const u32* __restrict__ flag,
                      void* __restrict__ out) {
  int n = blockIdx.x * blockDim.x + threadIdx.x;
  if (n >= N_NODES) return;
  float z = P[P_FB2];
  const float invN = 1.f / (float)N_NODES;
  const uint4* tv = (const uint4*)(t + (size_t)n * 64);
#pragma unroll 1
  for (int fb = 0; fb < 8; ++fb) {
    uint4 q = tv[fb];
    float v[8];
    up2(q.x, v[0], v[1]); up2(q.y, v[2], v[3]);
    up2(q.z, v[4], v[5]); up2(q.w, v[6], v[7]);
#pragma unroll
    for (int j = 0; j < 8; ++j) {
      int f = fb * 8 + j;
      float m = stats[f] * invN;
      float var = fmaxf(stats[64 + f] * invN - m * m, 0.f);
      float inv = rsqrtf(var + 1e-5f);
      float y = (v[j] - m) * inv * P[P_FG + f] + P[P_FBB + f];
      y = lrelu(y);
      z = fmaf(y, P[P_FW2 + f], z);
    }
  }
  float s = 1.f / (1.f + expf(-z));
  if (!(fabsf(z) < 1e30f)) s = 0.25f;
  if (*flag) ((float*)out)[n] = s;
  else       ((u16*)out)[n] = f2b(s);
}

extern "C" void kernel_launch(void* const* d_in, const int* in_sizes, int n_in,
                              void* d_out, int out_size, void* d_ws, size_t ws_size,
                              hipStream_t stream) {
  const int* node_deg = (const int*)d_in[0];
  const int* node_lab = (const int*)d_in[1];
  const int* edge     = (const int*)d_in[2];
  (void)in_sizes; (void)n_in; (void)out_size; (void)ws_size;

  char* base = (char*)d_ws;
  size_t off = 0;
  auto alloc = [&](size_t bytes) -> void* {
    void* p = base + off;
    off += (bytes + 15) & ~(size_t)15;
    return p;
  };
  float* Pb    = (float*)alloc((size_t)P_TOT * 4);
  u32* flag    = (u32*)alloc(16);
  float* W1p   = (float*)alloc(NCLS * 128 * 4);
  float* Efc   = (float*)alloc(NCLS * 64 * 4);
  float* stats = (float*)alloc(384 * 4);
  u32* deg     = (u32*)alloc((size_t)N_NODES * 4);
  u32* row_ptr = (u32*)alloc((size_t)(N_NODES + 1) * 4);
  u32* cursor  = (u32*)alloc((size_t)N_NODES * 4);
  u32* bsum    = (u32*)alloc(512 * 4);
  u32* colidx  = (u32*)alloc((size_t)N_EDGES * 4);
  u16* ccls    = (u16*)alloc((size_t)N_EDGES * 2);
  void* arena  = alloc((size_t)N_NODES * 128 * 2);  // hmid (25.6MB); later g1+abuf
  u16* h1      = (u16*)alloc((size_t)N_NODES * 64 * 2);
  u16* h2      = (u16*)alloc((size_t)N_NODES * 64 * 2);
  u16* t       = (u16*)alloc((size_t)N_NODES * 64 * 2);
  u16* hmid = (u16*)arena;                              // dead after k_mlp0b
  u16* g1   = (u16*)arena;                              // [N,64]
  u16* abuf = (u16*)arena + (size_t)N_NODES * 64;       // [N,64]
  // total ~72 MB

  hipMemsetAsync(flag, 0, 16, stream);
  hipMemsetAsync(stats, 0, 384 * 4, stream);
  hipMemsetAsync(deg, 0, (size_t)N_NODES * 4, stream);

  k_detect<<<1, 256, 0, stream>>>((const u16*)d_in[3], flag);

  CvtAll ca;
  const int srcidx[22] = {3, 4, 5, 6, 7, 8, 9, 10, 11, 12, 13, 14, 15, 16, 17, 18, 19, 20, 21, 22, 23, 24};
  const int cnts[22]   = {4160, 1024, 16384, 128, 8192, 64, 1, 64, 64, 4096, 64, 4096, 64, 1, 64, 64, 16384, 64, 64, 64, 64, 1};
  const int offs[22]   = {P_EMBD, P_EMBL, P_W1A, P_B1A, P_W2A, P_B2A, P_EPS0, P_G0, P_BB0,
                          P_LW1, P_LB1, P_LW2, P_LB2, P_EPS1, P_G1, P_BB1,
                          P_FW1, P_FB1, P_FG, P_FBB, P_FW2, P_FB2};
  for (int i = 0; i < 22; ++i) { ca.src[i] = d_in[srcidx[i]]; ca.cnt[i] = cnts[i]; ca.off[i] = offs[i]; }
  k_cvtall<<<dim3(64, 22), 256, 0, stream>>>(ca, flag, Pb);

  k_pre1<<<(NCLS * 128 + 255) / 256, 256, 0, stream>>>(Pb, W1p);
  k_pre2<<<(NCLS * 64 + 255) / 256, 256, 0, stream>>>(Pb, Efc);

  // CSR build
  k_deg<<<(N_EDGES + 255) / 256, 256, 0, stream>>>(edge, deg);
  k_scan1<<<NBLK_SCAN, 256, 0, stream>>>(deg, row_ptr, bsum);
  k_scan2<<<1, 512, 0, stream>>>(bsum, row_ptr);
  k_scan3<<<NBLK_SCAN, 256, 0, stream>>>(row_ptr, bsum, cursor);
  k_fill<<<(N_EDGES + 255) / 256, 256, 0, stream>>>(edge, node_deg, node_lab, cursor, colidx, ccls);

  // layer 0: W1p-row aggregation (LDS) -> hmid, then GEMM -> t, BN -> h1
  k_agg0<<<(N_NODES + 63) / 64, 256, 0, stream>>>(row_ptr, ccls, node_deg, node_lab, W1p, Pb, hmid);
  k_mlp0b<<<(N_NODES + 63) / 64, 256, 0, stream>>>(hmid, Pb, t);
  k_bnstats<<<256, 256, 0, stream>>>(t, stats);
  k_bnfin<<<(N_NODES * 64 + 255) / 256, 256, 0, stream>>>(t, stats, Pb, P_G0, P_BB0, h1);

  // layer 1: GEMM-first, aggregate after
  k_g1<<<(N_NODES + 63) / 64, 256, 0, stream>>>(h1, Pb, g1);
  k_agg1<<<(N_NODES + 3) / 4, 256, 0, stream>>>(row_ptr, colidx, g1, Pb, abuf);
  k_g2<<<(N_NODES + 63) / 64, 256, 0, stream>>>(abuf, Pb, t);
  k_bnstats<<<256, 256, 0, stream>>>(t, stats + 128);
  k_bnfin<<<(N_NODES * 64 + 255) / 256, 256, 0, stream>>>(t, stats + 128, Pb, P_G1, P_BB1, h2);

  // FC head
  k_fc1b<<<(N_NODES + 63) / 64, 256, 0, stream>>>(node_deg, node_lab, Efc, h1, h2, Pb, t);
  k_bnstats<<<256, 256, 0, stream>>>(t, stats + 256);
  k_fc2<<<(N_NODES + 255) / 256, 256, 0, stream>>>(t, stats + 256, Pb, flag, d_out);
}

// Round 5
// 567.866 us; speedup vs baseline: 1.5241x; 1.3365x over previous
//
#include <hip/hip_runtime.h>

#define N_NODES 100000
#define N_EDGES 1200000
#define NCLS 81  // 65 deg classes + 16 lab classes

typedef unsigned short u16;
typedef unsigned int u32;
typedef short bf16x8 __attribute__((ext_vector_type(8)));
typedef float f32x4 __attribute__((ext_vector_type(4)));

__device__ __forceinline__ float b2f(u16 u) {
  union { u32 i; float f; } v; v.i = ((u32)u) << 16; return v.f;
}
__device__ __forceinline__ u16 f2b(float f) {
  union { float f; u32 i; } v; v.f = f;
  u32 x = v.i;
  return (u16)((x + 0x7fffu + ((x >> 16) & 1u)) >> 16);
}
__device__ __forceinline__ u32 pk2(float lo, float hi) {
  return (u32)f2b(lo) | ((u32)f2b(hi) << 16);
}
__device__ __forceinline__ float lrelu(float x) { return x > 0.f ? x : 0.01f * x; }

// ---- fp32 param block offsets ----
#define P_EMBD 0       // 4160
#define P_EMBL 4160    // 1024
#define P_W1A  5184    // 16384  l0_w1 (128x128)
#define P_B1A  21568   // 128
#define P_W2A  21696   // 8192   l0_w2 (128x64)
#define P_B2A  29888   // 64
#define P_EPS0 29952   // 1
#define P_G0   29953   // 64
#define P_BB0  30017   // 64
#define P_LW1  30081   // 4096   l1_w1 (64x64)
#define P_LB1  34177   // 64
#define P_LW2  34241   // 4096   l1_w2 (64x64)
#define P_LB2  38337   // 64
#define P_EPS1 38401   // 1
#define P_G1   38402   // 64
#define P_BB1  38466   // 64
#define P_FW1  38530   // 16384  fc_w1 (256x64)
#define P_FB1  54914   // 64
#define P_FG   54978   // 64
#define P_FBB  55042   // 64
#define P_FW2  55106   // 64
#define P_FB2  55170   // 1
#define P_TOT  55171

// ---------------- dtype detection ----------------
__global__ void k_detect(const u16* __restrict__ e, u32* __restrict__ flag) {
  u32 t = 0;
  for (int k = threadIdx.x; k < 4096; k += 256) {
    u32 ex = (e[k] >> 7) & 0xFF;
    if (ex >= 0x90) t = 1;
  }
  if (t) atomicOr(flag, 1u);
}

// ---------------- convert all float params to fp32 block ----------------
struct CvtAll {
  const void* src[22];
  int cnt[22];
  int off[22];
};

__global__ void k_cvtall(CvtAll a, const u32* __restrict__ flag, float* __restrict__ P) {
  int seg = blockIdx.y;
  int i = blockIdx.x * 256 + threadIdx.x;
  if (i >= a.cnt[seg]) return;
  float v;
  if (*flag) v = ((const float*)a.src[seg])[i];
  else       v = b2f(((const u16*)a.src[seg])[i]);
  P[a.off[seg] + i] = v;
}

// W1p[c][h] = (E @ l0_w1)[c][h]
__global__ void k_pre1(const float* __restrict__ P, float* __restrict__ W1p) {
  int idx = blockIdx.x * blockDim.x + threadIdx.x;
  if (idx >= NCLS * 128) return;
  int c = idx >> 7, h = idx & 127;
  const float* w1 = P + P_W1A;
  float s = 0.f;
  if (c < 65) {
    const float* em = P + P_EMBD + c * 64;
    for (int k = 0; k < 64; ++k) s = fmaf(em[k], w1[k * 128 + h], s);
  } else {
    const float* em = P + P_EMBL + (c - 65) * 64;
    for (int k = 0; k < 64; ++k) s = fmaf(em[k], w1[(64 + k) * 128 + h], s);
  }
  W1p[idx] = s;
}

// Efc[c][o] = (E @ fc_w1[0:128,:])[c][o]
__global__ void k_pre2(const float* __restrict__ P, float* __restrict__ Efc) {
  int idx = blockIdx.x * blockDim.x + threadIdx.x;
  if (idx >= NCLS * 64) return;
  int c = idx >> 6, o = idx & 63;
  const float* fw = P + P_FW1;
  float s = 0.f;
  if (c < 65) {
    const float* em = P + P_EMBD + c * 64;
    for (int k = 0; k < 64; ++k) s = fmaf(em[k], fw[k * 64 + o], s);
  } else {
    const float* em = P + P_EMBL + (c - 65) * 64;
    for (int k = 0; k < 64; ++k) s = fmaf(em[k], fw[(64 + k) * 64 + o], s);
  }
  Efc[idx] = s;
}

// ---------------- pack weights into MFMA B-fragment order (bf16) ----------------
// B-frag for 16x16x32: lane holds B[k = (lane>>4)*8 + j][n = lane&15], j=0..7
// bp layout: ((nt*KB + kb)*64 + lane)*8 + j
__global__ void k_pack(const float* __restrict__ P, u16* __restrict__ bp) {
  int idx = blockIdx.x * 256 + threadIdx.x;
  int seg, rel;
  if (idx < 8192)       { seg = 0; rel = idx; }
  else if (idx < 12288) { seg = 1; rel = idx - 8192; }
  else if (idx < 16384) { seg = 2; rel = idx - 12288; }
  else if (idx < 24576) { seg = 3; rel = idx - 16384; }
  else return;
  const int srcoff[4] = {P_W2A, P_LW1, P_LW2, P_FW1 + 128 * 64};
  const int KBs[4] = {4, 2, 2, 4};
  int j = rel & 7, lane = (rel >> 3) & 63, rest = rel >> 9;
  int kb = rest % KBs[seg], nt = rest / KBs[seg];
  int k = kb * 32 + (lane >> 4) * 8 + j;
  int n = nt * 16 + (lane & 15);
  bp[idx] = f2b(P[srcoff[seg] + k * 64 + n]);
}

// ---------------- in-degree ----------------
__global__ void k_deg(const int* __restrict__ edge, u32* __restrict__ deg) {
  int e = blockIdx.x * 256 + threadIdx.x;
  if (e >= N_EDGES) return;
  atomicAdd(&deg[edge[N_EDGES + e]], 1u);
}

// ---------------- CSR build: scan of deg ----------------
__global__ void k_scan1(const u32* __restrict__ deg, u32* __restrict__ row_ptr,
                        u32* __restrict__ bsum) {
  __shared__ u32 l[256];
  int tid = threadIdx.x;
  int i = blockIdx.x * 256 + tid;
  u32 v = (i < N_NODES) ? deg[i] : 0u;
  l[tid] = v;
  __syncthreads();
  for (int off = 1; off < 256; off <<= 1) {
    u32 a = (tid >= off) ? l[tid - off] : 0u;
    __syncthreads();
    l[tid] += a;
    __syncthreads();
  }
  if (i < N_NODES) row_ptr[i] = l[tid] - v;
  if (tid == 255) bsum[blockIdx.x] = l[255];
}

#define NBLK_SCAN 391

__global__ void k_scan2(u32* __restrict__ bsum, u32* __restrict__ row_ptr) {
  __shared__ u32 l[512];
  int tid = threadIdx.x;
  u32 v = (tid < NBLK_SCAN) ? bsum[tid] : 0u;
  l[tid] = v;
  __syncthreads();
  for (int off = 1; off < 512; off <<= 1) {
    u32 a = (tid >= off) ? l[tid - off] : 0u;
    __syncthreads();
    l[tid] += a;
    __syncthreads();
  }
  if (tid < NBLK_SCAN) bsum[tid] = l[tid] - v;
  if (tid == NBLK_SCAN - 1) row_ptr[N_NODES] = l[tid];
}

__global__ void k_scan3(u32* __restrict__ row_ptr, const u32* __restrict__ bsum,
                        u32* __restrict__ cursor) {
  int i = blockIdx.x * 256 + threadIdx.x;
  if (i >= N_NODES) return;
  u32 v = row_ptr[i] + bsum[i >> 8];
  row_ptr[i] = v;
  cursor[i] = v;
}

// ---------------- CSR fill ----------------
__global__ void k_fill(const int* __restrict__ edge, const int* __restrict__ ndeg,
                       const int* __restrict__ nlab, u32* __restrict__ cursor,
                       u32* __restrict__ colidx, u16* __restrict__ ccls) {
  int e = blockIdx.x * 256 + threadIdx.x;
  if (e >= N_EDGES) return;
  int s = edge[e], d = edge[N_EDGES + e];
  u32 pos = atomicAdd(&cursor[d], 1u);
  colidx[pos] = (u32)s;
  ccls[pos] = (u16)((ndeg[s] << 4) | nlab[s]);
}

// ---------------- layer-0 aggregation: LDS-resident W1p row gather ----------------
__global__ __launch_bounds__(256) void k_agg0(const u32* __restrict__ row_ptr,
                                              const u16* __restrict__ ccls,
                                              const int* __restrict__ ndeg,
                                              const int* __restrict__ nlab,
                                              const float* __restrict__ W1p,
                                              const float* __restrict__ P,
                                              u16* __restrict__ hmid) {
  __shared__ float w[NCLS * 128];
  for (int i = threadIdx.x; i < NCLS * 32; i += 256)
    ((float4*)w)[i] = ((const float4*)W1p)[i];
  __syncthreads();
  const float2* w2 = (const float2*)w;
  int lane = threadIdx.x & 63, wv = threadIdx.x >> 6;
  float onep = 1.f + P[P_EPS0];
  float2 b1v = ((const float2*)(P + P_B1A))[lane];
#pragma unroll 1
  for (int it = 0; it < 16; ++it) {
    int n = blockIdx.x * 64 + it * 4 + wv;
    if (n >= N_NODES) continue;
    int dn = ndeg[n], ln = 65 + nlab[n];
    float2 vd = w2[dn * 64 + lane];
    float2 vl = w2[ln * 64 + lane];
    float a0 = b1v.x + onep * (vd.x + vl.x);
    float a1 = b1v.y + onep * (vd.y + vl.y);
    u32 b0 = row_ptr[n], b1 = row_ptr[n + 1];
    for (u32 base = b0; base < b1; base += 64) {
      u32 m = b1 - base; if (m > 64u) m = 64u;
      u32 myc = ((u32)lane < m) ? (u32)ccls[base + lane] : 0u;
      for (u32 kk = 0; kk < m; ++kk) {
        u32 cc = (u32)__builtin_amdgcn_readlane((int)myc, (int)kk);
        int cd = (int)(cc >> 4), cl = 65 + (int)(cc & 15u);
        float2 xd = w2[cd * 64 + lane];
        float2 xl = w2[cl * 64 + lane];
        a0 += xd.x + xl.x;
        a1 += xd.y + xl.y;
      }
    }
    ((u32*)hmid)[(size_t)n * 64 + lane] = pk2(lrelu(a0), lrelu(a1));
  }
}

// ---------------- MFMA GEMM: C[100k,64] = A[100k,K] @ B + (bias) ----------------
// wave = 16 nodes x 64 outs; A bf16 row-major lda elements; Bp prepacked.
template <int KB, int LDA, int BIASOFF>
__global__ __launch_bounds__(256) void k_gemm(const u16* __restrict__ A,
                                              const u16* __restrict__ Bp,
                                              const float* __restrict__ P,
                                              u16* __restrict__ C) {
  int wid = threadIdx.x >> 6, lane = threadIdx.x & 63;
  int m0 = (blockIdx.x * 4 + wid) * 16;
  if (m0 >= N_NODES) return;
  int row = lane & 15, q = lane >> 4;
  const u16* ap = A + (size_t)(m0 + row) * LDA + q * 8;
  const bf16x8* bp = (const bf16x8*)Bp;
  f32x4 acc[4];
#pragma unroll
  for (int nt = 0; nt < 4; ++nt) {
    float b = (BIASOFF >= 0) ? P[BIASOFF + nt * 16 + row] : 0.f;
    acc[nt][0] = b; acc[nt][1] = b; acc[nt][2] = b; acc[nt][3] = b;
  }
#pragma unroll
  for (int kb = 0; kb < KB; ++kb) {
    bf16x8 af = *(const bf16x8*)(ap + kb * 32);
#pragma unroll
    for (int nt = 0; nt < 4; ++nt) {
      bf16x8 bf = bp[(nt * KB + kb) * 64 + lane];
      acc[nt] = __builtin_amdgcn_mfma_f32_16x16x32_bf16(af, bf, acc[nt], 0, 0, 0);
    }
  }
#pragma unroll
  for (int nt = 0; nt < 4; ++nt)
#pragma unroll
    for (int r = 0; r < 4; ++r) {
      int m = m0 + q * 4 + r;
      C[(size_t)m * 64 + nt * 16 + row] = f2b(acc[nt][r]);
    }
}

// fc1 variant: + Efc[dn]+Efc[ln] row add in epilogue
__global__ __launch_bounds__(256) void k_gemm_fc1(const u16* __restrict__ A,
                                                  const u16* __restrict__ Bp,
                                                  const float* __restrict__ P,
                                                  const int* __restrict__ ndeg,
                                                  const int* __restrict__ nlab,
                                                  const float* __restrict__ Efc,
                                                  u16* __restrict__ C) {
  const int KB = 4, LDA = 128;
  int wid = threadIdx.x >> 6, lane = threadIdx.x & 63;
  int m0 = (blockIdx.x * 4 + wid) * 16;
  if (m0 >= N_NODES) return;
  int row = lane & 15, q = lane >> 4;
  const u16* ap = A + (size_t)(m0 + row) * LDA + q * 8;
  const bf16x8* bp = (const bf16x8*)Bp;
  f32x4 acc[4];
#pragma unroll
  for (int nt = 0; nt < 4; ++nt) {
    float b = P[P_FB1 + nt * 16 + row];
    acc[nt][0] = b; acc[nt][1] = b; acc[nt][2] = b; acc[nt][3] = b;
  }
#pragma unroll
  for (int kb = 0; kb < KB; ++kb) {
    bf16x8 af = *(const bf16x8*)(ap + kb * 32);
#pragma unroll
    for (int nt = 0; nt < 4; ++nt) {
      bf16x8 bf = bp[(nt * KB + kb) * 64 + lane];
      acc[nt] = __builtin_amdgcn_mfma_f32_16x16x32_bf16(af, bf, acc[nt], 0, 0, 0);
    }
  }
#pragma unroll
  for (int r = 0; r < 4; ++r) {
    int m = m0 + q * 4 + r;
    int dn = ndeg[m], ln = 65 + nlab[m];
#pragma unroll
    for (int nt = 0; nt < 4; ++nt) {
      int cc = nt * 16 + row;
      float v = acc[nt][r] + Efc[dn * 64 + cc] + Efc[ln * 64 + cc];
      C[(size_t)m * 64 + cc] = f2b(v);
    }
  }
}

// a[n] = lrelu(b1 + (1+eps1)*g1[n] + sum_nbr g1[nbr])
__global__ __launch_bounds__(256) void k_agg1(const u32* __restrict__ row_ptr,
                                              const u32* __restrict__ colidx,
                                              const u16* __restrict__ g1,
                                              const float* __restrict__ P,
                                              u16* __restrict__ abuf) {
  int lane = threadIdx.x & 63, wv = threadIdx.x >> 6;
  int n = blockIdx.x * 4 + wv;
  if (n >= N_NODES) return;
  u32 b0 = row_ptr[n], b1 = row_ptr[n + 1];
  u32 m = b1 - b0;
  float acc = 0.f;
  u32 k = 0;
  for (; k + 4 <= m; k += 4) {
    u32 c0 = colidx[b0 + k], c1 = colidx[b0 + k + 1];
    u32 c2 = colidx[b0 + k + 2], c3 = colidx[b0 + k + 3];
    float v0 = b2f(g1[(size_t)c0 * 64 + lane]);
    float v1 = b2f(g1[(size_t)c1 * 64 + lane]);
    float v2 = b2f(g1[(size_t)c2 * 64 + lane]);
    float v3 = b2f(g1[(size_t)c3 * 64 + lane]);
    acc += (v0 + v1) + (v2 + v3);
  }
  for (; k < m; ++k) acc += b2f(g1[(size_t)colidx[b0 + k] * 64 + lane]);
  float onep = 1.f + P[P_EPS1];
  float a = P[P_LB1 + lane] + fmaf(onep, b2f(g1[(size_t)n * 64 + lane]), acc);
  abuf[(size_t)n * 64 + lane] = f2b(lrelu(a));
}

// ---------------- BatchNorm stats over bf16 t ----------------
__global__ void k_bnstats(const u16* __restrict__ t, float* __restrict__ stats) {
  __shared__ float ls[256], lq[256];
  int tid = threadIdx.x;
  int f = tid & 63, rg = tid >> 6;
  float s = 0.f, q = 0.f;
  for (int n = blockIdx.x * 4 + rg; n < N_NODES; n += gridDim.x * 4) {
    float v = b2f(t[(size_t)n * 64 + f]);
    s += v;
    q = fmaf(v, v, q);
  }
  ls[tid] = s; lq[tid] = q;
  __syncthreads();
  if (tid < 64) {
    s = ls[tid] + ls[tid + 64] + ls[tid + 128] + ls[tid + 192];
    q = lq[tid] + lq[tid + 64] + lq[tid + 128] + lq[tid + 192];
    atomicAdd(&stats[f], s);
    atomicAdd(&stats[64 + f], q);
  }
}

// ---------------- BN finalize + lrelu -> h12 (stride 128, offset dof) ----------------
__global__ void k_bnfin(const u16* __restrict__ t, const float* __restrict__ stats,
                        const float* __restrict__ P, int goff, int boff,
                        u16* __restrict__ h, int dof) {
  int idx = blockIdx.x * blockDim.x + threadIdx.x;
  if (idx >= N_NODES * 64) return;
  int f = idx & 63, n = idx >> 6;
  const float invN = 1.f / (float)N_NODES;
  float m = stats[f] * invN;
  float var = fmaxf(stats[64 + f] * invN - m * m, 0.f);
  float inv = rsqrtf(var + 1e-5f);
  float v = (b2f(t[idx]) - m) * inv * P[goff + f] + P[boff + f];
  v = lrelu(v);
  if (!(fabsf(v) < 1e30f)) v = 999.0f;
  h[(size_t)n * 128 + dof + f] = f2b(v);
}

// ---------------- FC final: BN + lrelu + dot + sigmoid ----------------
__global__ void k_fc2(const u16* __restrict__ t, const float* __restrict__ stats,
                      const float* __restrict__ P, const u32* __restrict__ flag,
                      void* __restrict__ out) {
  int n = blockIdx.x * blockDim.x + threadIdx.x;
  if (n >= N_NODES) return;
  float z = P[P_FB2];
  const float invN = 1.f / (float)N_NODES;
  const u16* tn = t + (size_t)n * 64;
#pragma unroll 1
  for (int f = 0; f < 64; ++f) {
    float m = stats[f] * invN;
    float var = fmaxf(stats[64 + f] * invN - m * m, 0.f);
    float inv = rsqrtf(var + 1e-5f);
    float y = (b2f(tn[f]) - m) * inv * P[P_FG + f] + P[P_FBB + f];
    y = lrelu(y);
    z = fmaf(y, P[P_FW2 + f], z);
  }
  float s = 1.f / (1.f + expf(-z));
  if (!(fabsf(z) < 1e30f)) s = 0.25f;
  if (*flag) ((float*)out)[n] = s;
  else       ((u16*)out)[n] = f2b(s);
}

extern "C" void kernel_launch(void* const* d_in, const int* in_sizes, int n_in,
                              void* d_out, int out_size, void* d_ws, size_t ws_size,
                              hipStream_t stream) {
  const int* node_deg = (const int*)d_in[0];
  const int* node_lab = (const int*)d_in[1];
  const int* edge     = (const int*)d_in[2];
  (void)in_sizes; (void)n_in; (void)out_size; (void)ws_size;

  char* base = (char*)d_ws;
  size_t off = 0;
  auto alloc = [&](size_t bytes) -> void* {
    void* p = base + off;
    off += (bytes + 15) & ~(size_t)15;
    return p;
  };
  float* Pb    = (float*)alloc((size_t)P_TOT * 4);
  u32* flag    = (u32*)alloc(16);
  float* W1p   = (float*)alloc(NCLS * 128 * 4);
  float* Efc   = (float*)alloc(NCLS * 64 * 4);
  u16* bpack   = (u16*)alloc(24576 * 2);
  float* stats = (float*)alloc(384 * 4);
  u32* deg     = (u32*)alloc((size_t)N_NODES * 4);
  u32* row_ptr = (u32*)alloc((size_t)(N_NODES + 1) * 4);
  u32* cursor  = (u32*)alloc((size_t)N_NODES * 4);
  u32* bsum    = (u32*)alloc(512 * 4);
  u32* colidx  = (u32*)alloc((size_t)N_EDGES * 4);
  u16* ccls    = (u16*)alloc((size_t)N_EDGES * 2);
  void* arena  = alloc((size_t)N_NODES * 128 * 2);  // hmid; later g1+abuf
  u16* h12     = (u16*)alloc((size_t)N_NODES * 128 * 2);
  u16* t       = (u16*)alloc((size_t)N_NODES * 64 * 2);
  u16* hmid = (u16*)arena;
  u16* g1   = (u16*)arena;
  u16* abuf = (u16*)arena + (size_t)N_NODES * 64;
  u16* Bp_w2a = bpack;           // 8192
  u16* Bp_lw1 = bpack + 8192;    // 4096
  u16* Bp_lw2 = bpack + 12288;   // 4096
  u16* Bp_fw1 = bpack + 16384;   // 8192
  // total ~73 MB

  hipMemsetAsync(flag, 0, 16, stream);
  hipMemsetAsync(stats, 0, 384 * 4, stream);
  hipMemsetAsync(deg, 0, (size_t)N_NODES * 4, stream);

  k_detect<<<1, 256, 0, stream>>>((const u16*)d_in[3], flag);

  CvtAll ca;
  const int srcidx[22] = {3, 4, 5, 6, 7, 8, 9, 10, 11, 12, 13, 14, 15, 16, 17, 18, 19, 20, 21, 22, 23, 24};
  const int cnts[22]   = {4160, 1024, 16384, 128, 8192, 64, 1, 64, 64, 4096, 64, 4096, 64, 1, 64, 64, 16384, 64, 64, 64, 64, 1};
  const int offs[22]   = {P_EMBD, P_EMBL, P_W1A, P_B1A, P_W2A, P_B2A, P_EPS0, P_G0, P_BB0,
                          P_LW1, P_LB1, P_LW2, P_LB2, P_EPS1, P_G1, P_BB1,
                          P_FW1, P_FB1, P_FG, P_FBB, P_FW2, P_FB2};
  for (int i = 0; i < 22; ++i) { ca.src[i] = d_in[srcidx[i]]; ca.cnt[i] = cnts[i]; ca.off[i] = offs[i]; }
  k_cvtall<<<dim3(64, 22), 256, 0, stream>>>(ca, flag, Pb);

  k_pre1<<<(NCLS * 128 + 255) / 256, 256, 0, stream>>>(Pb, W1p);
  k_pre2<<<(NCLS * 64 + 255) / 256, 256, 0, stream>>>(Pb, Efc);
  k_pack<<<96, 256, 0, stream>>>(Pb, bpack);

  // CSR build
  k_deg<<<(N_EDGES + 255) / 256, 256, 0, stream>>>(edge, deg);
  k_scan1<<<NBLK_SCAN, 256, 0, stream>>>(deg, row_ptr, bsum);
  k_scan2<<<1, 512, 0, stream>>>(bsum, row_ptr);
  k_scan3<<<NBLK_SCAN, 256, 0, stream>>>(row_ptr, bsum, cursor);
  k_fill<<<(N_EDGES + 255) / 256, 256, 0, stream>>>(edge, node_deg, node_lab, cursor, colidx, ccls);

  const int GEMM_GRID = (6250 + 3) / 4;  // 100000/16 wave-tiles / 4 waves per block

  // layer 0
  k_agg0<<<(N_NODES + 63) / 64, 256, 0, stream>>>(row_ptr, ccls, node_deg, node_lab, W1p, Pb, hmid);
  k_gemm<4, 128, P_B2A><<<GEMM_GRID, 256, 0, stream>>>(hmid, Bp_w2a, Pb, t);
  k_bnstats<<<256, 256, 0, stream>>>(t, stats);
  k_bnfin<<<(N_NODES * 64 + 255) / 256, 256, 0, stream>>>(t, stats, Pb, P_G0, P_BB0, h12, 0);

  // layer 1: GEMM-first, aggregate after
  k_gemm<2, 128, -1><<<GEMM_GRID, 256, 0, stream>>>(h12, Bp_lw1, Pb, g1);
  k_agg1<<<(N_NODES + 3) / 4, 256, 0, stream>>>(row_ptr, colidx, g1, Pb, abuf);
  k_gemm<2, 64, P_LB2><<<GEMM_GRID, 256, 0, stream>>>(abuf, Bp_lw2, Pb, t);
  k_bnstats<<<256, 256, 0, stream>>>(t, stats + 128);
  k_bnfin<<<(N_NODES * 64 + 255) / 256, 256, 0, stream>>>(t, stats + 128, Pb, P_G1, P_BB1, h12, 64);

  // FC head
  k_gemm_fc1<<<GEMM_GRID, 256, 0, stream>>>(h12, Bp_fw1, Pb, node_deg, node_lab, Efc, t);
  k_bnstats<<<256, 256, 0, stream>>>(t, stats + 256);
  k_fc2<<<(N_NODES + 255) / 256, 256, 0, stream>>>(t, stats + 256, Pb, flag, d_out);
}